// Round 1
// baseline (507.569 us; speedup 1.0000x reference)
//
#include <hip/hip_runtime.h>
#include <math.h>

// SpaceFillingVQ: N=65536 rows, D=64, E=4096 entries.
// d_in: [0] input_data (N*D f32), [1] codebook (E*D f32), [2] dither (E-1 f32), [3] entries (int,1)
// d_out: quantized (N*D f32) | perplexity (1 f32) | integer_index (N f32)

constexpr int D = 64;
constexpr int ESLICES = 4;
constexpr int TILE = 64;      // codebook entries per LDS tile
constexpr int BLK = 128;      // threads in vq_partial; each thread owns 2 rows

// ---------------- Kernel 1: dithered codebook + c2 ----------------
__global__ __launch_bounds__(64) void build_dcb_kernel(
    const float* __restrict__ cb, const float* __restrict__ dither,
    float* __restrict__ dcb, float* __restrict__ c2, int E, int Em1) {
  int i = blockIdx.x;
  int k = threadIdx.x;
  if (i >= Em1) return;
  // exactly replicate reference f32 arithmetic (frac can round up to i+1!)
  float frac = dither[i] + (float)i;
  int ii = (int)floorf(frac);
  ii = max(0, min(ii, E - 2));
  float r = frac - (float)ii;
  float v = (1.0f - r) * cb[(size_t)ii * D + k] + r * cb[(size_t)(ii + 1) * D + k];
  dcb[(size_t)i * D + k] = v;
  float s = v * v;
#pragma unroll
  for (int off = 32; off > 0; off >>= 1) s += __shfl_down(s, off, 64);
  if (k == 0) c2[i] = s;
}

// ---------------- Kernel 2: partial distance argmin over an E-slice ----------------
// grid (N/256, ESLICES), block 128. Thread t handles rows base+t and base+t+128.
__global__ __launch_bounds__(BLK) void vq_partial_kernel(
    const float* __restrict__ X, const float* __restrict__ dcb,
    const float* __restrict__ c2,
    float* __restrict__ pdist, int* __restrict__ pidx, int N, int Em1) {
  __shared__ float s_cb[TILE * D];
  __shared__ float s_c2[TILE];

  const int slice = blockIdx.y;
  const int per = (Em1 + ESLICES - 1) / ESLICES;
  const int j0 = slice * per;
  const int j1 = min(j0 + per, Em1);

  const int base = blockIdx.x * (2 * BLK);
  const int row0 = base + threadIdx.x;
  const int row1 = row0 + BLK;

  float4 x0[16], x1[16];
  {
    const float4* p0 = (const float4*)(X + (size_t)row0 * D);
    const float4* p1 = (const float4*)(X + (size_t)row1 * D);
#pragma unroll
    for (int i = 0; i < 16; ++i) { x0[i] = p0[i]; x1[i] = p1[i]; }
  }

  float best0 = 3.4e38f, best1 = 3.4e38f;
  int bi0 = 0, bi1 = 0;

  for (int t0 = j0; t0 < j1; t0 += TILE) {
    const int cnt = min(TILE, j1 - t0);
    __syncthreads();
    {
      const float4* cp = (const float4*)(dcb + (size_t)t0 * D);
      float4* sp = (float4*)s_cb;
      for (int i = threadIdx.x; i < cnt * (D / 4); i += BLK) sp[i] = cp[i];
      for (int i = threadIdx.x; i < cnt; i += BLK) s_c2[i] = c2[t0 + i];
    }
    __syncthreads();

    for (int j = 0; j < cnt; ++j) {
      const float4* cb4 = (const float4*)(s_cb + j * D);
      float a0 = 0.f, a1 = 0.f, a2 = 0.f, a3 = 0.f;
      float b0 = 0.f, b1 = 0.f, b2 = 0.f, b3 = 0.f;
#pragma unroll
      for (int i = 0; i < 16; ++i) {
        float4 c = cb4[i];
        a0 = fmaf(x0[i].x, c.x, a0);
        a1 = fmaf(x0[i].y, c.y, a1);
        a2 = fmaf(x0[i].z, c.z, a2);
        a3 = fmaf(x0[i].w, c.w, a3);
        b0 = fmaf(x1[i].x, c.x, b0);
        b1 = fmaf(x1[i].y, c.y, b1);
        b2 = fmaf(x1[i].z, c.z, b2);
        b3 = fmaf(x1[i].w, c.w, b3);
      }
      float dot0 = (a0 + a1) + (a2 + a3);
      float dot1 = (b0 + b1) + (b2 + b3);
      float cc = s_c2[j];
      float d0 = cc - 2.0f * dot0;
      float d1 = cc - 2.0f * dot1;
      if (d0 < best0) { best0 = d0; bi0 = t0 + j; }  // strict < keeps first min (argmin semantics)
      if (d1 < best1) { best1 = d1; bi1 = t0 + j; }
    }
  }

  pdist[(size_t)slice * N + row0] = best0;
  pidx [(size_t)slice * N + row0] = bi0;
  pdist[(size_t)slice * N + row1] = best1;
  pidx [(size_t)slice * N + row1] = bi1;
}

// ---------------- Kernel 3: combine slices, write idx + quantized, histogram ----------------
// grid N/64, block 64 (one wave)
__global__ __launch_bounds__(64) void vq_finish_kernel(
    const float* __restrict__ pdist, const int* __restrict__ pidx,
    const float* __restrict__ dcb,
    float* __restrict__ outq, float* __restrict__ outidx,
    float* __restrict__ counts, int N) {
  const int lane = threadIdx.x;
  const int rowbase = blockIdx.x * 64;
  const int row = rowbase + lane;

  float best = 3.4e38f;
  int bi = 0;
  // ascending slice order + strict < preserves first-occurrence argmin across slices
#pragma unroll
  for (int s = 0; s < ESLICES; ++s) {
    float d = pdist[(size_t)s * N + row];
    int i = pidx[(size_t)s * N + row];
    if (d < best) { best = d; bi = i; }
  }
  outidx[row] = (float)bi;
  atomicAdd(&counts[bi], 1.0f);  // sums of 1.0f are exact -> deterministic

  // cooperative coalesced quantized write: for each of the wave's 64 rows,
  // all 64 lanes copy one element of dcb[idx_r]
  for (int r = 0; r < 64; ++r) {
    int idx_r = __shfl(bi, r, 64);
    outq[(size_t)(rowbase + r) * D + lane] = dcb[(size_t)idx_r * D + lane];
  }
}

// ---------------- Kernel 4: perplexity ----------------
__global__ __launch_bounds__(256) void vq_perp_kernel(
    const float* __restrict__ counts, float* __restrict__ out, int E, float invN) {
  __shared__ float red[4];
  float s = 0.f;
  for (int j = threadIdx.x; j < E; j += 256) {
    float p = counts[j] * invN;
    s += p * logf(p + 1e-10f);
  }
#pragma unroll
  for (int off = 32; off > 0; off >>= 1) s += __shfl_down(s, off, 64);
  int wid = threadIdx.x >> 6;
  if ((threadIdx.x & 63) == 0) red[wid] = s;
  __syncthreads();
  if (threadIdx.x == 0) {
    float t = (red[0] + red[1]) + (red[2] + red[3]);
    out[0] = expf(-t);
  }
}

static inline size_t align256(size_t x) { return (x + 255) & ~(size_t)255; }

extern "C" void kernel_launch(void* const* d_in, const int* in_sizes, int n_in,
                              void* d_out, int out_size, void* d_ws, size_t ws_size,
                              hipStream_t stream) {
  const float* X      = (const float*)d_in[0];
  const float* cb     = (const float*)d_in[1];
  const float* dither = (const float*)d_in[2];

  const int N   = in_sizes[0] / D;       // 65536
  const int E   = in_sizes[1] / D;       // 4096
  const int Em1 = in_sizes[2];           // 4095

  // workspace layout
  char* w = (char*)d_ws;
  float* dcb    = (float*)w;  w += align256((size_t)Em1 * D * sizeof(float));
  float* c2     = (float*)w;  w += align256((size_t)Em1 * sizeof(float));
  float* pdist  = (float*)w;  w += align256((size_t)ESLICES * N * sizeof(float));
  int*   pidx   = (int*)w;    w += align256((size_t)ESLICES * N * sizeof(int));
  float* counts = (float*)w;  w += align256((size_t)E * sizeof(float));

  float* outq   = (float*)d_out;
  float* perp   = (float*)d_out + (size_t)N * D;
  float* outidx = (float*)d_out + (size_t)N * D + 1;

  hipMemsetAsync(counts, 0, (size_t)E * sizeof(float), stream);

  build_dcb_kernel<<<Em1, 64, 0, stream>>>(cb, dither, dcb, c2, E, Em1);

  dim3 g2(N / (2 * BLK), ESLICES);
  vq_partial_kernel<<<g2, BLK, 0, stream>>>(X, dcb, c2, pdist, pidx, N, Em1);

  vq_finish_kernel<<<N / 64, 64, 0, stream>>>(pdist, pidx, dcb, outq, outidx, counts, N);

  vq_perp_kernel<<<1, 256, 0, stream>>>(counts, perp, E, 1.0f / (float)N);
}

// Round 3
// 360.718 us; speedup vs baseline: 1.4071x; 1.4071x over previous
//
#include <hip/hip_runtime.h>
#include <math.h>

// SpaceFillingVQ: N=65536 rows, D=64, E=4096 entries.
// Strategy: bf16-split (3-term) MFMA distance pass tracking best+second-best,
// exact fp32 rescue for rows whose gap < TAU. Argmin semantics preserved.

constexpr int D = 64;
constexpr int CHUNK = 128;          // codebook entries staged in LDS per iteration
constexpr int NTILES = CHUNK / 16;  // 16-entry MFMA tiles per chunk
constexpr int E_PAD = 4096;
constexpr float TAU = 0.03f;        // distance-domain gap threshold for rescue

typedef __attribute__((ext_vector_type(8))) short bf16x8;
typedef __attribute__((ext_vector_type(4))) float f32x4;

__device__ inline unsigned short f2bf(float x) {  // round-to-nearest-even bf16
  unsigned int u = __float_as_uint(x);
  u = (u + 0x7fffu + ((u >> 16) & 1u)) >> 16;
  return (unsigned short)u;
}
__device__ inline float bf2f(unsigned short h) {
  return __uint_as_float(((unsigned int)h) << 16);
}

// ---------------- Kernel 1: dithered codebook (f32 + bf16 hi/lo split) + c2/2 ----
__global__ __launch_bounds__(64) void build_kernel(
    const float* __restrict__ cb, const float* __restrict__ dither,
    float* __restrict__ dcb, unsigned short* __restrict__ dcbh,
    unsigned short* __restrict__ dcbl, float* __restrict__ c2h, int E, int Em1) {
  int i = blockIdx.x;
  int k = threadIdx.x;
  if (i >= Em1) {  // pad entries: never selectable
    dcb[(size_t)i * D + k] = 0.f;
    dcbh[(size_t)i * D + k] = 0;
    dcbl[(size_t)i * D + k] = 0;
    if (k == 0) c2h[i] = 3.0e38f;
    return;
  }
  float frac = dither[i] + (float)i;  // replicate reference f32 arithmetic
  int ii = (int)floorf(frac);
  ii = max(0, min(ii, E - 2));
  float r = frac - (float)ii;
  float v = (1.0f - r) * cb[(size_t)ii * D + k] + r * cb[(size_t)(ii + 1) * D + k];
  dcb[(size_t)i * D + k] = v;
  unsigned short h = f2bf(v);
  unsigned short l = f2bf(v - bf2f(h));
  dcbh[(size_t)i * D + k] = h;
  dcbl[(size_t)i * D + k] = l;
  float s = v * v;
#pragma unroll
  for (int off = 32; off > 0; off >>= 1) s += __shfl_down(s, off, 64);
  if (k == 0) c2h[i] = 0.5f * s;
}

// ---------------- Kernel 2: MFMA distance + best/second-best per row ----------
// block = 512 threads = 8 waves; each wave owns 16 rows; all E entries scanned.
// maximize s = dot - c2/2  (dist = -2s + x2); track (b1,i1) and b2 value.
__global__ __launch_bounds__(512) void vq_mfma_kernel(
    const float* __restrict__ X, const unsigned short* __restrict__ dcbh,
    const unsigned short* __restrict__ dcbl, const float* __restrict__ c2h,
    int* __restrict__ out_i1, float* __restrict__ out_gap, int N) {
  __shared__ unsigned short s_h[CHUNK * D];
  __shared__ unsigned short s_l[CHUNK * D];
  __shared__ float s_c2[CHUNK];

  const int tid = threadIdx.x;
  const int lane = tid & 63;
  const int wv = tid >> 6;
  const int col = lane & 15;   // MFMA col / A-row within 16
  const int kg = lane >> 4;    // k-group 0..3
  const int rowbase = blockIdx.x * 128 + wv * 16;

  // ---- A fragments: rows in registers, bf16 hi/lo, 2 K-tiles (k 0-31, 32-63)
  const float* xp = X + (size_t)(rowbase + col) * D + kg * 8;
  bf16x8 ah0, ah1, al0, al1;
#pragma unroll
  for (int i = 0; i < 8; ++i) {
    float x0 = xp[i], x1 = xp[32 + i];
    unsigned short h0 = f2bf(x0), h1 = f2bf(x1);
    ah0[i] = (short)h0; ah1[i] = (short)h1;
    al0[i] = (short)f2bf(x0 - bf2f(h0));
    al1[i] = (short)f2bf(x1 - bf2f(h1));
  }

  float b1[4], b2[4];
  int i1[4];
#pragma unroll
  for (int r = 0; r < 4; ++r) { b1[r] = -3.4e38f; b2[r] = -3.4e38f; i1[r] = 0; }

  const int xs = col & 7;  // XOR-swizzle key (entry&7 within tile == col&7)

  for (int ch = 0; ch < E_PAD / CHUNK; ++ch) {
    const int ebase = ch * CHUNK;
    __syncthreads();
    // stage chunk, XOR-swizzled: byte slot g of entry e lands at ((g^(e&7))<<4)
    for (int u = tid; u < CHUNK * 8; u += 512) {
      int e = u >> 3, g = u & 7;
      int wa = e * 128 + ((g ^ (e & 7)) << 4);
      *(uint4*)((char*)s_h + wa) = *(const uint4*)(dcbh + ((size_t)(ebase + e) << 6) + g * 8);
      *(uint4*)((char*)s_l + wa) = *(const uint4*)(dcbl + ((size_t)(ebase + e) << 6) + g * 8);
    }
    for (int u = tid; u < CHUNK; u += 512) s_c2[u] = c2h[ebase + u];
    __syncthreads();

#pragma unroll
    for (int t = 0; t < NTILES; ++t) {
      const int el = t * 16 + col;
      const char* bb = (const char*)s_h + el * 128;
      const char* ll = (const char*)s_l + el * 128;
      bf16x8 bh0 = *(const bf16x8*)(bb + (((kg) ^ xs) << 4));
      bf16x8 bh1 = *(const bf16x8*)(bb + (((kg + 4) ^ xs) << 4));
      bf16x8 bl0 = *(const bf16x8*)(ll + (((kg) ^ xs) << 4));
      bf16x8 bl1 = *(const bf16x8*)(ll + (((kg + 4) ^ xs) << 4));
      f32x4 acc0 = {0.f, 0.f, 0.f, 0.f}, acc1 = {0.f, 0.f, 0.f, 0.f};
      acc0 = __builtin_amdgcn_mfma_f32_16x16x32_bf16(ah0, bh0, acc0, 0, 0, 0);
      acc1 = __builtin_amdgcn_mfma_f32_16x16x32_bf16(ah1, bh1, acc1, 0, 0, 0);
      acc0 = __builtin_amdgcn_mfma_f32_16x16x32_bf16(ah0, bl0, acc0, 0, 0, 0);
      acc1 = __builtin_amdgcn_mfma_f32_16x16x32_bf16(ah1, bl1, acc1, 0, 0, 0);
      acc0 = __builtin_amdgcn_mfma_f32_16x16x32_bf16(al0, bh0, acc0, 0, 0, 0);
      acc1 = __builtin_amdgcn_mfma_f32_16x16x32_bf16(al1, bh1, acc1, 0, 0, 0);
      float hc2 = s_c2[el];
      int colg = ebase + el;
#pragma unroll
      for (int r = 0; r < 4; ++r) {
        float s = (acc0[r] + acc1[r]) - hc2;
        bool gt = s > b1[r];                       // strict > keeps first occurrence
        b2[r] = fmaxf(b2[r], fminf(s, b1[r]));     // merged second-best
        b1[r] = fmaxf(b1[r], s);
        i1[r] = gt ? colg : i1[r];
      }
    }
  }

  // cross-lane reduce over 16 cols (xor within lane&15; same row group = lane>>4)
#pragma unroll
  for (int m = 1; m < 16; m <<= 1) {
#pragma unroll
    for (int r = 0; r < 4; ++r) {
      float ob1 = __shfl_xor(b1[r], m, 64);
      float ob2 = __shfl_xor(b2[r], m, 64);
      int oi1 = __shfl_xor(i1[r], m, 64);
      float loser = fminf(b1[r], ob1);
      b2[r] = fmaxf(fmaxf(b2[r], ob2), loser);
      bool take = (ob1 > b1[r]) || (ob1 == b1[r] && oi1 < i1[r]);
      b1[r] = take ? ob1 : b1[r];
      i1[r] = take ? oi1 : i1[r];
    }
  }
  if (col == 0) {
#pragma unroll
    for (int r = 0; r < 4; ++r) {
      int row = rowbase + kg * 4 + r;  // row = (lane>>4)*4 + reg (verified C/D map)
      out_i1[row] = i1[r];
      out_gap[row] = b1[r] - b2[r];    // s-domain gap; dist gap = 2x
    }
  }
}

// ---------------- Kernel 3: finalize rows, histogram, quantized gather --------
__global__ __launch_bounds__(64) void finish_kernel(
    const int* __restrict__ out_i1, const float* __restrict__ out_gap,
    const float* __restrict__ dcb, float* __restrict__ outq,
    float* __restrict__ outidx, float* __restrict__ counts,
    int* __restrict__ rescue_n, int* __restrict__ rescue_list, int N) {
  const int lane = threadIdx.x;
  const int rowbase = blockIdx.x * 64;
  const int row = rowbase + lane;
  int bi = out_i1[row];
  float gap2 = 2.0f * out_gap[row];
  outidx[row] = (float)bi;  // tentative for flagged rows; rescue overwrites
  if (gap2 < TAU) {
    int p = atomicAdd(rescue_n, 1);
    rescue_list[p] = row;
  } else {
    atomicAdd(&counts[bi], 1.0f);  // exact sums of 1.0f
  }
  for (int r = 0; r < 64; ++r) {
    int idx_r = __shfl(bi, r, 64);
    outq[(size_t)(rowbase + r) * D + lane] = dcb[(size_t)idx_r * D + lane];
  }
}

// ---------------- Kernel 4: exact fp32 rescue for near-tie rows ---------------
__global__ __launch_bounds__(256) void rescue_kernel(
    const float* __restrict__ X, const float* __restrict__ dcb,
    const float* __restrict__ c2h, const int* __restrict__ rescue_n,
    const int* __restrict__ rescue_list, float* __restrict__ outq,
    float* __restrict__ outidx, float* __restrict__ counts, int Em1) {
  __shared__ float sx[D];
  __shared__ float sd[4];
  __shared__ int si[4];
  __shared__ int sbest;
  const int tid = threadIdx.x;
  const int nr = *rescue_n;
  for (int li = blockIdx.x; li < nr; li += gridDim.x) {
    const int row = rescue_list[li];
    __syncthreads();
    if (tid < D) sx[tid] = X[(size_t)row * D + tid];
    __syncthreads();
    float best = 3.4e38f;
    int bidx = 0x7fffffff;
    for (int e = tid; e < Em1; e += 256) {  // ascending per thread -> first-min ok
      const float* cp = dcb + (size_t)e * D;
      float dot = 0.f;
#pragma unroll
      for (int k = 0; k < D; ++k) dot = fmaf(sx[k], cp[k], dot);
      float d = c2h[e] - dot;  // monotone in true distance
      if (d < best) { best = d; bidx = e; }
    }
    for (int m = 1; m < 64; m <<= 1) {
      float od = __shfl_xor(best, m, 64);
      int oi = __shfl_xor(bidx, m, 64);
      if (od < best || (od == best && oi < bidx)) { best = od; bidx = oi; }
    }
    if ((tid & 63) == 0) { sd[tid >> 6] = best; si[tid >> 6] = bidx; }
    __syncthreads();
    if (tid == 0) {
      float bb = sd[0]; int bi2 = si[0];
      for (int w = 1; w < 4; ++w)
        if (sd[w] < bb || (sd[w] == bb && si[w] < bi2)) { bb = sd[w]; bi2 = si[w]; }
      sbest = bi2;
      outidx[row] = (float)bi2;
      atomicAdd(&counts[bi2], 1.0f);
    }
    __syncthreads();
    int bfin = sbest;
    if (tid < D) outq[(size_t)row * D + tid] = dcb[(size_t)bfin * D + tid];
  }
}

// ---------------- Kernel 5: perplexity ----------------------------------------
__global__ __launch_bounds__(256) void vq_perp_kernel(
    const float* __restrict__ counts, float* __restrict__ out, int E, float invN) {
  __shared__ float red[4];
  float s = 0.f;
  for (int j = threadIdx.x; j < E; j += 256) {
    float p = counts[j] * invN;
    s += p * logf(p + 1e-10f);
  }
#pragma unroll
  for (int off = 32; off > 0; off >>= 1) s += __shfl_down(s, off, 64);
  int wid = threadIdx.x >> 6;
  if ((threadIdx.x & 63) == 0) red[wid] = s;
  __syncthreads();
  if (threadIdx.x == 0) {
    float t = (red[0] + red[1]) + (red[2] + red[3]);
    out[0] = expf(-t);
  }
}

static inline size_t align256(size_t x) { return (x + 255) & ~(size_t)255; }

extern "C" void kernel_launch(void* const* d_in, const int* in_sizes, int n_in,
                              void* d_out, int out_size, void* d_ws, size_t ws_size,
                              hipStream_t stream) {
  const float* X      = (const float*)d_in[0];
  const float* cb     = (const float*)d_in[1];
  const float* dither = (const float*)d_in[2];

  const int N   = in_sizes[0] / D;  // 65536
  const int E   = in_sizes[1] / D;  // 4096
  const int Em1 = in_sizes[2];      // 4095

  char* w = (char*)d_ws;
  float* dcb            = (float*)w;          w += align256((size_t)E_PAD * D * sizeof(float));
  unsigned short* dcbh  = (unsigned short*)w; w += align256((size_t)E_PAD * D * sizeof(short));
  unsigned short* dcbl  = (unsigned short*)w; w += align256((size_t)E_PAD * D * sizeof(short));
  float* c2h            = (float*)w;          w += align256((size_t)E_PAD * sizeof(float));
  int* out_i1           = (int*)w;            w += align256((size_t)N * sizeof(int));
  float* out_gap        = (float*)w;          w += align256((size_t)N * sizeof(float));
  float* counts         = (float*)w;          w += align256((size_t)E_PAD * sizeof(float));
  int* rescue_n         = (int*)w;            w += align256(sizeof(int));
  int* rescue_list      = (int*)w;            w += align256((size_t)N * sizeof(int));

  float* outq   = (float*)d_out;
  float* perp   = (float*)d_out + (size_t)N * D;
  float* outidx = (float*)d_out + (size_t)N * D + 1;

  hipMemsetAsync(counts, 0, (size_t)E_PAD * sizeof(float), stream);
  hipMemsetAsync(rescue_n, 0, sizeof(int), stream);

  build_kernel<<<E_PAD, 64, 0, stream>>>(cb, dither, dcb, dcbh, dcbl, c2h, E, Em1);

  vq_mfma_kernel<<<N / 128, 512, 0, stream>>>(X, dcbh, dcbl, c2h, out_i1, out_gap, N);

  finish_kernel<<<N / 64, 64, 0, stream>>>(out_i1, out_gap, dcb, outq, outidx, counts,
                                           rescue_n, rescue_list, N);

  rescue_kernel<<<128, 256, 0, stream>>>(X, dcb, c2h, rescue_n, rescue_list,
                                         outq, outidx, counts, Em1);

  vq_perp_kernel<<<1, 256, 0, stream>>>(counts, perp, E, 1.0f / (float)N);
}

// Round 4
// 215.087 us; speedup vs baseline: 2.3598x; 1.6771x over previous
//
#include <hip/hip_runtime.h>
#include <math.h>

// SpaceFillingVQ: N=65536 rows, D=64, E=4096 entries.
// bf16-split (3-term) MFMA distance pass tracking best+second-best,
// exact fp32 rescue (parallel scan) for rows whose gap < TAU.

constexpr int D = 64;
constexpr int CHUNK = 128;          // codebook entries staged in LDS per iteration
constexpr int NTILES = CHUNK / 16;  // 16-entry MFMA tiles per chunk
constexpr int E_PAD = 4096;
constexpr float TAU = 0.01f;        // distance-domain gap threshold for rescue
constexpr int NSLICE = 8;
constexpr int SLICE_E = E_PAD / NSLICE;  // 512 entries per rescue slice

typedef __attribute__((ext_vector_type(8))) short bf16x8;
typedef __attribute__((ext_vector_type(4))) float f32x4;

__device__ inline unsigned short f2bf(float x) {  // round-to-nearest-even bf16
  unsigned int u = __float_as_uint(x);
  u = (u + 0x7fffu + ((u >> 16) & 1u)) >> 16;
  return (unsigned short)u;
}
__device__ inline float bf2f(unsigned short h) {
  return __uint_as_float(((unsigned int)h) << 16);
}

// ---------------- Kernel 1: dithered codebook (f32 + bf16 hi/lo split) + c2/2 ----
__global__ __launch_bounds__(64) void build_kernel(
    const float* __restrict__ cb, const float* __restrict__ dither,
    float* __restrict__ dcb, unsigned short* __restrict__ dcbh,
    unsigned short* __restrict__ dcbl, float* __restrict__ c2h, int E, int Em1) {
  int i = blockIdx.x;
  int k = threadIdx.x;
  if (i >= Em1) {  // pad entries: never selectable
    dcb[(size_t)i * D + k] = 0.f;
    dcbh[(size_t)i * D + k] = 0;
    dcbl[(size_t)i * D + k] = 0;
    if (k == 0) c2h[i] = 3.0e38f;
    return;
  }
  float frac = dither[i] + (float)i;  // replicate reference f32 arithmetic
  int ii = (int)floorf(frac);
  ii = max(0, min(ii, E - 2));
  float r = frac - (float)ii;
  float v = (1.0f - r) * cb[(size_t)ii * D + k] + r * cb[(size_t)(ii + 1) * D + k];
  dcb[(size_t)i * D + k] = v;
  unsigned short h = f2bf(v);
  unsigned short l = f2bf(v - bf2f(h));
  dcbh[(size_t)i * D + k] = h;
  dcbl[(size_t)i * D + k] = l;
  float s = v * v;
#pragma unroll
  for (int off = 32; off > 0; off >>= 1) s += __shfl_down(s, off, 64);
  if (k == 0) c2h[i] = 0.5f * s;
}

// ---------------- Kernel 2: MFMA distance + best/second-best per row ----------
// block = 512 threads = 8 waves; each wave owns 16 rows; all E entries scanned.
// maximize s = dot - c2/2  (dist = -2s + x2); track (b1,i1) and b2 value.
__global__ __launch_bounds__(512) void vq_mfma_kernel(
    const float* __restrict__ X, const unsigned short* __restrict__ dcbh,
    const unsigned short* __restrict__ dcbl, const float* __restrict__ c2h,
    int* __restrict__ out_i1, float* __restrict__ out_gap, int N) {
  __shared__ unsigned short s_h[CHUNK * D];
  __shared__ unsigned short s_l[CHUNK * D];
  __shared__ float s_c2[CHUNK];

  const int tid = threadIdx.x;
  const int lane = tid & 63;
  const int wv = tid >> 6;
  const int col = lane & 15;   // MFMA col / A-row within 16
  const int kg = lane >> 4;    // k-group 0..3
  const int rowbase = blockIdx.x * 128 + wv * 16;

  // ---- A fragments: rows in registers, bf16 hi/lo, 2 K-tiles (k 0-31, 32-63)
  const float* xp = X + (size_t)(rowbase + col) * D + kg * 8;
  bf16x8 ah0, ah1, al0, al1;
#pragma unroll
  for (int i = 0; i < 8; ++i) {
    float x0 = xp[i], x1 = xp[32 + i];
    unsigned short h0 = f2bf(x0), h1 = f2bf(x1);
    ah0[i] = (short)h0; ah1[i] = (short)h1;
    al0[i] = (short)f2bf(x0 - bf2f(h0));
    al1[i] = (short)f2bf(x1 - bf2f(h1));
  }

  float b1[4], b2[4];
  int i1[4];
#pragma unroll
  for (int r = 0; r < 4; ++r) { b1[r] = -3.4e38f; b2[r] = -3.4e38f; i1[r] = 0; }

  const int xs = col & 7;  // XOR-swizzle key (entry&7 within tile == col&7)

  for (int ch = 0; ch < E_PAD / CHUNK; ++ch) {
    const int ebase = ch * CHUNK;
    __syncthreads();
    // stage chunk, XOR-swizzled: byte slot g of entry e lands at ((g^(e&7))<<4)
    for (int u = tid; u < CHUNK * 8; u += 512) {
      int e = u >> 3, g = u & 7;
      int wa = e * 128 + ((g ^ (e & 7)) << 4);
      *(uint4*)((char*)s_h + wa) = *(const uint4*)(dcbh + ((size_t)(ebase + e) << 6) + g * 8);
      *(uint4*)((char*)s_l + wa) = *(const uint4*)(dcbl + ((size_t)(ebase + e) << 6) + g * 8);
    }
    for (int u = tid; u < CHUNK; u += 512) s_c2[u] = c2h[ebase + u];
    __syncthreads();

#pragma unroll
    for (int t = 0; t < NTILES; ++t) {
      const int el = t * 16 + col;
      const char* bb = (const char*)s_h + el * 128;
      const char* ll = (const char*)s_l + el * 128;
      bf16x8 bh0 = *(const bf16x8*)(bb + (((kg) ^ xs) << 4));
      bf16x8 bh1 = *(const bf16x8*)(bb + (((kg + 4) ^ xs) << 4));
      bf16x8 bl0 = *(const bf16x8*)(ll + (((kg) ^ xs) << 4));
      bf16x8 bl1 = *(const bf16x8*)(ll + (((kg + 4) ^ xs) << 4));
      f32x4 acc0 = {0.f, 0.f, 0.f, 0.f}, acc1 = {0.f, 0.f, 0.f, 0.f};
      acc0 = __builtin_amdgcn_mfma_f32_16x16x32_bf16(ah0, bh0, acc0, 0, 0, 0);
      acc1 = __builtin_amdgcn_mfma_f32_16x16x32_bf16(ah1, bh1, acc1, 0, 0, 0);
      acc0 = __builtin_amdgcn_mfma_f32_16x16x32_bf16(ah0, bl0, acc0, 0, 0, 0);
      acc1 = __builtin_amdgcn_mfma_f32_16x16x32_bf16(ah1, bl1, acc1, 0, 0, 0);
      acc0 = __builtin_amdgcn_mfma_f32_16x16x32_bf16(al0, bh0, acc0, 0, 0, 0);
      acc1 = __builtin_amdgcn_mfma_f32_16x16x32_bf16(al1, bh1, acc1, 0, 0, 0);
      float hc2 = s_c2[el];
      int colg = ebase + el;
#pragma unroll
      for (int r = 0; r < 4; ++r) {
        float s = (acc0[r] + acc1[r]) - hc2;
        bool gt = s > b1[r];                       // strict > keeps first occurrence
        b2[r] = fmaxf(b2[r], fminf(s, b1[r]));     // merged second-best
        b1[r] = fmaxf(b1[r], s);
        i1[r] = gt ? colg : i1[r];
      }
    }
  }

  // cross-lane reduce over 16 cols (xor within lane&15; same row group = lane>>4)
#pragma unroll
  for (int m = 1; m < 16; m <<= 1) {
#pragma unroll
    for (int r = 0; r < 4; ++r) {
      float ob1 = __shfl_xor(b1[r], m, 64);
      float ob2 = __shfl_xor(b2[r], m, 64);
      int oi1 = __shfl_xor(i1[r], m, 64);
      float loser = fminf(b1[r], ob1);
      b2[r] = fmaxf(fmaxf(b2[r], ob2), loser);
      bool take = (ob1 > b1[r]) || (ob1 == b1[r] && oi1 < i1[r]);
      b1[r] = take ? ob1 : b1[r];
      i1[r] = take ? oi1 : i1[r];
    }
  }
  if (col == 0) {
#pragma unroll
    for (int r = 0; r < 4; ++r) {
      int row = rowbase + kg * 4 + r;  // row = (lane>>4)*4 + reg (verified C/D map)
      out_i1[row] = i1[r];
      out_gap[row] = b1[r] - b2[r];    // s-domain gap; dist gap = 2x
    }
  }
}

// ---------------- Kernel 3: finalize rows, histogram, quantized gather --------
__global__ __launch_bounds__(64) void finish_kernel(
    const int* __restrict__ out_i1, const float* __restrict__ out_gap,
    const float* __restrict__ dcb, float* __restrict__ outq,
    float* __restrict__ outidx, float* __restrict__ counts,
    int* __restrict__ rescue_n, int* __restrict__ rescue_list, int N) {
  const int lane = threadIdx.x;
  const int rowbase = blockIdx.x * 64;
  const int row = rowbase + lane;
  int bi = out_i1[row];
  float gap2 = 2.0f * out_gap[row];
  outidx[row] = (float)bi;  // tentative for flagged rows; rescue overwrites
  if (gap2 < TAU) {
    int p = atomicAdd(rescue_n, 1);
    rescue_list[p] = row;
  } else {
    atomicAdd(&counts[bi], 1.0f);  // exact sums of 1.0f
  }
  for (int r = 0; r < 64; ++r) {
    int idx_r = __shfl(bi, r, 64);
    outq[(size_t)(rowbase + r) * D + lane] = dcb[(size_t)idx_r * D + lane];
  }
}

// ---------------- Kernel 4a: parallel exact rescue scan -----------------------
// One wave per (rescued row, 512-entry slice) unit. X row hoisted to registers
// (broadcast loads); each lane scans 8 entries with float4 codebook loads.
__global__ __launch_bounds__(64) void rescue_scan_kernel(
    const float* __restrict__ X, const float* __restrict__ dcb,
    const float* __restrict__ c2h, const int* __restrict__ rescue_n,
    const int* __restrict__ rescue_list,
    float* __restrict__ pd, int* __restrict__ pi) {
  const int lane = threadIdx.x;
  const int nu = (*rescue_n) * NSLICE;
  for (int u = blockIdx.x; u < nu; u += gridDim.x) {
    const int li = u >> 3;
    const int sl = u & (NSLICE - 1);
    const int row = rescue_list[li];

    const float4* xr = (const float4*)(X + (size_t)row * D);
    float4 x[16];
#pragma unroll
    for (int k = 0; k < 16; ++k) x[k] = xr[k];  // wave-uniform broadcast loads

    float best = 3.4e38f;
    int bidx = 0x7fffffff;
    const int e0 = sl * SLICE_E;
#pragma unroll 2
    for (int j = 0; j < SLICE_E / 64; ++j) {
      const int e = e0 + j * 64 + lane;  // ascending per lane -> strict < = first min
      const float4* cp = (const float4*)(dcb + (size_t)e * D);
      float d0 = 0.f, d1 = 0.f, d2 = 0.f, d3 = 0.f;
#pragma unroll
      for (int k = 0; k < 16; ++k) {
        float4 c = cp[k];
        d0 = fmaf(x[k].x, c.x, d0);
        d1 = fmaf(x[k].y, c.y, d1);
        d2 = fmaf(x[k].z, c.z, d2);
        d3 = fmaf(x[k].w, c.w, d3);
      }
      float d = c2h[e] - ((d0 + d1) + (d2 + d3));  // monotone in true distance
      if (d < best) { best = d; bidx = e; }
    }
    // wave lex-min (dist, idx)
#pragma unroll
    for (int m = 1; m < 64; m <<= 1) {
      float od = __shfl_xor(best, m, 64);
      int oi = __shfl_xor(bidx, m, 64);
      if (od < best || (od == best && oi < bidx)) { best = od; bidx = oi; }
    }
    if (lane == 0) { pd[u] = best; pi[u] = bidx; }
  }
}

// ---------------- Kernel 4b: rescue finalize ----------------------------------
__global__ __launch_bounds__(64) void rescue_fin_kernel(
    const float* __restrict__ dcb, const int* __restrict__ rescue_n,
    const int* __restrict__ rescue_list, const float* __restrict__ pd,
    const int* __restrict__ pi, float* __restrict__ outq,
    float* __restrict__ outidx, float* __restrict__ counts) {
  const int lane = threadIdx.x;
  const int nr = *rescue_n;
  for (int li = blockIdx.x; li < nr; li += gridDim.x) {
    const int row = rescue_list[li];
    float d = (lane < NSLICE) ? pd[li * NSLICE + lane] : 3.5e38f;
    int ix = (lane < NSLICE) ? pi[li * NSLICE + lane] : 0x7fffffff;
#pragma unroll
    for (int m = 1; m < NSLICE; m <<= 1) {
      float od = __shfl_xor(d, m, 64);
      int oi = __shfl_xor(ix, m, 64);
      if (od < d || (od == d && oi < ix)) { d = od; ix = oi; }
    }
    int bfin = __shfl(ix, 0, 64);
    if (lane == 0) {
      outidx[row] = (float)bfin;
      atomicAdd(&counts[bfin], 1.0f);
    }
    outq[(size_t)row * D + lane] = dcb[(size_t)bfin * D + lane];
  }
}

// ---------------- Kernel 5: perplexity ----------------------------------------
__global__ __launch_bounds__(256) void vq_perp_kernel(
    const float* __restrict__ counts, float* __restrict__ out, int E, float invN) {
  __shared__ float red[4];
  float s = 0.f;
  for (int j = threadIdx.x; j < E; j += 256) {
    float p = counts[j] * invN;
    s += p * logf(p + 1e-10f);
  }
#pragma unroll
  for (int off = 32; off > 0; off >>= 1) s += __shfl_down(s, off, 64);
  int wid = threadIdx.x >> 6;
  if ((threadIdx.x & 63) == 0) red[wid] = s;
  __syncthreads();
  if (threadIdx.x == 0) {
    float t = (red[0] + red[1]) + (red[2] + red[3]);
    out[0] = expf(-t);
  }
}

static inline size_t align256(size_t x) { return (x + 255) & ~(size_t)255; }

extern "C" void kernel_launch(void* const* d_in, const int* in_sizes, int n_in,
                              void* d_out, int out_size, void* d_ws, size_t ws_size,
                              hipStream_t stream) {
  const float* X      = (const float*)d_in[0];
  const float* cb     = (const float*)d_in[1];
  const float* dither = (const float*)d_in[2];

  const int N   = in_sizes[0] / D;  // 65536
  const int E   = in_sizes[1] / D;  // 4096
  const int Em1 = in_sizes[2];      // 4095

  char* w = (char*)d_ws;
  float* dcb            = (float*)w;          w += align256((size_t)E_PAD * D * sizeof(float));
  unsigned short* dcbh  = (unsigned short*)w; w += align256((size_t)E_PAD * D * sizeof(short));
  unsigned short* dcbl  = (unsigned short*)w; w += align256((size_t)E_PAD * D * sizeof(short));
  float* c2h            = (float*)w;          w += align256((size_t)E_PAD * sizeof(float));
  int* out_i1           = (int*)w;            w += align256((size_t)N * sizeof(int));
  float* out_gap        = (float*)w;          w += align256((size_t)N * sizeof(float));
  float* counts         = (float*)w;          w += align256((size_t)E_PAD * sizeof(float));
  int* rescue_n         = (int*)w;            w += align256(sizeof(int));
  int* rescue_list      = (int*)w;            w += align256((size_t)N * sizeof(int));
  float* pd             = (float*)w;          w += align256((size_t)N * NSLICE * sizeof(float));
  int* pi               = (int*)w;            w += align256((size_t)N * NSLICE * sizeof(int));

  float* outq   = (float*)d_out;
  float* perp   = (float*)d_out + (size_t)N * D;
  float* outidx = (float*)d_out + (size_t)N * D + 1;

  hipMemsetAsync(counts, 0, (size_t)E_PAD * sizeof(float), stream);
  hipMemsetAsync(rescue_n, 0, sizeof(int), stream);

  build_kernel<<<E_PAD, 64, 0, stream>>>(cb, dither, dcb, dcbh, dcbl, c2h, E, Em1);

  vq_mfma_kernel<<<N / 128, 512, 0, stream>>>(X, dcbh, dcbl, c2h, out_i1, out_gap, N);

  finish_kernel<<<N / 64, 64, 0, stream>>>(out_i1, out_gap, dcb, outq, outidx, counts,
                                           rescue_n, rescue_list, N);

  rescue_scan_kernel<<<2048, 64, 0, stream>>>(X, dcb, c2h, rescue_n, rescue_list, pd, pi);

  rescue_fin_kernel<<<1024, 64, 0, stream>>>(dcb, rescue_n, rescue_list, pd, pi,
                                             outq, outidx, counts);

  vq_perp_kernel<<<1, 256, 0, stream>>>(counts, perp, E, 1.0f / (float)N);
}